// Round 1
// 997.698 us; speedup vs baseline: 1.5169x; 1.5169x over previous
//
#include <hip/hip_runtime.h>
#include <math.h>

#define NPERSEG 30
#define STEPW 15
#define NSEG 3
#define NF 16
#define PATCH 60
#define STRIDE 30
#define NP_ROW 199
#define NBATCH 1024
#define T_LEN 6000
#define NPATCH_TOTAL (NBATCH * NP_ROW)   /* 203776 = 796 * 256 */
#define NBLOCKS (NPATCH_TOTAL / 256)
#define TP 16
#define NGRP (256 / TP)

// f64 twiddles cos/sin(2*pi*m/30), correctly-rounded decimal literals.
// Differences vs the previous runtime device-cos table are <=1 ulp f64
// (1e-16 rel) -> invisible at the f32 comparison level.
constexpr double TC[30] = {
  1.0,
  0.97814760073380563793,
  0.91354545764260089550,
  0.80901699437494742410,
  0.66913060635885821383,
  0.5,
  0.30901699437494742410,
  0.10452846326765347140,
 -0.10452846326765347140,
 -0.30901699437494742410,
 -0.5,
 -0.66913060635885821383,
 -0.80901699437494742410,
 -0.91354545764260089550,
 -0.97814760073380563793,
 -1.0,
 -0.97814760073380563793,
 -0.91354545764260089550,
 -0.80901699437494742410,
 -0.66913060635885821383,
 -0.5,
 -0.30901699437494742410,
 -0.10452846326765347140,
  0.10452846326765347140,
  0.30901699437494742410,
  0.5,
  0.66913060635885821383,
  0.80901699437494742410,
  0.91354545764260089550,
  0.97814760073380563793,
};
constexpr double TS[30] = {
  0.0,
  0.20791169081775933710,
  0.40673664307580020775,
  0.58778525229247312917,
  0.74314482547739423501,
  0.86602540378443864676,
  0.95105651629515357212,
  0.99452189536827333692,
  0.99452189536827333692,
  0.95105651629515357212,
  0.86602540378443864676,
  0.74314482547739423501,
  0.58778525229247312917,
  0.40673664307580020775,
  0.20791169081775933710,
  0.0,
 -0.20791169081775933710,
 -0.40673664307580020775,
 -0.58778525229247312917,
 -0.74314482547739423501,
 -0.86602540378443864676,
 -0.95105651629515357212,
 -0.99452189536827333692,
 -0.99452189536827333692,
 -0.95105651629515357212,
 -0.86602540378443864676,
 -0.74314482547739423501,
 -0.58778525229247312917,
 -0.40673664307580020775,
 -0.20791169081775933710,
};
// WIN_NORM = 200 * sum(hann^2) = 2250 exactly (periodic hann, N=30: 0.375*N).
// f64-accumulated value differs by ~1e-13 abs -> 1e-16 rel on psd: negligible.
constexpr double INV_WN = 1.0 / 2250.0;
constexpr double THIRD  = 1.0 / 3.0;

// numpy's pairwise f32 sum for n=30 (loops.c.src): 8 partials over 24 elems,
// fixed combine tree, then 6 sequential tail adds.
__device__ __forceinline__ float np_sum30_f32(const float* a) {
    float r[8];
#pragma unroll
    for (int j = 0; j < 8; ++j) r[j] = a[j];
#pragma unroll
    for (int i = 8; i < 24; i += 8)
#pragma unroll
        for (int j = 0; j < 8; ++j) r[j] += a[i + j];
    float res = ((r[0] + r[1]) + (r[2] + r[3])) + ((r[4] + r[5]) + (r[6] + r[7]));
#pragma unroll
    for (int i = 24; i < 30; ++i) res += a[i];
    return res;
}

// numpy pairwise f64 sum for n=16
__device__ __forceinline__ double np_sum16_f64(const double* a) {
    double r[8];
#pragma unroll
    for (int j = 0; j < 8; ++j) r[j] = a[j] + a[8 + j];
    return ((r[0] + r[1]) + (r[2] + r[3])) + ((r[4] + r[5]) + (r[6] + r[7]));
}

__global__ __launch_bounds__(256, 3) void fused_kernel(
    const float* __restrict__ x,
    const float* __restrict__ g_m, const float* __restrict__ b_m,
    const float* __restrict__ g_s, const float* __restrict__ b_s,
    const float* __restrict__ W1, const float* __restrict__ b1,
    const float* __restrict__ W2, const float* __restrict__ b2,
    const float* __restrict__ g_o, const float* __restrict__ b_o,
    float* __restrict__ out)
{
    __shared__ float Fs[256][22];
    __shared__ float Hs[TP][128];
    __shared__ float red1[TP][4], red2[TP][4];

    const int tid = threadIdx.x;

    // ================= phase 1: one thread = one patch =================
    const int g   = blockIdx.x * 256 + tid;
    const int bb_ = g / NP_ROW;
    const int pi  = g - bb_ * NP_ROW;
    const float* xp = x + (size_t)bb_ * T_LEN + (size_t)pi * STRIDE;

    // ---- morph (f64 continuous; discrete decisions input-exact) ----
    double morph[13];
    {
        float pf[PATCH];
#pragma unroll
        for (int n = 0; n < PATCH; ++n) pf[n] = xp[n];

        double vmax = (double)pf[0], vmin = vmax, vsum = 0.0;
#pragma unroll
        for (int n = 0; n < PATCH; ++n) {
            double v = (double)pf[n];
            vmax = fmax(vmax, v); vmin = fmin(vmin, v); vsum += v;
        }
        double vmean = vsum / 60.0;
        double s2 = 0.0, s3 = 0.0, s4 = 0.0, ssq = 0.0;
#pragma unroll
        for (int n = 0; n < PATCH; ++n) {
            double v = (double)pf[n];
            double c = v - vmean, c2 = c * c;
            s2 += c2; s3 += c2 * c; s4 += c2 * c2;
            ssq += v * v;
        }
        double m2 = s2 / 60.0, m3 = s3 / 60.0, m4 = s4 / 60.0;
        double vstd = sqrt(m2);

        int amax = 0; float aval = fabsf(pf[0]);
#pragma unroll
        for (int n = 1; n < PATCH; ++n) {
            float a = fabsf(pf[n]);
            if (a > aval) { aval = a; amax = n; }
        }
        double peak_loc = (double)((float)amax / 60.0f);

        double dmax = (double)pf[1] - (double)pf[0], dmin = dmax, dabssum = 0.0;
#pragma unroll
        for (int n = 0; n < PATCH - 1; ++n) {
            double d = (double)pf[n + 1] - (double)pf[n];
            dmax = fmax(dmax, d); dmin = fmin(dmin, d); dabssum += fabs(d);
        }
        double dabsmean = dabssum / 59.0;

        int zc = 0;
        {
            float v0 = pf[0] + 1e-10f;
            int prev = (v0 > 0.0f) - (v0 < 0.0f);
#pragma unroll
            for (int n = 1; n < PATCH; ++n) {
                float v = pf[n] + 1e-10f;
                int s = (v > 0.0f) - (v < 0.0f);
                if (s != prev) zc++;
                prev = s;
            }
        }
        double zcf = (double)zc / 60.0;
        double kurt = m4 / (m2 * m2) - 3.0;
        double skew = m3 / (m2 * sqrt(m2));

        morph[0] = vmax;  morph[1] = vmin;  morph[2] = vmax - vmin;
        morph[3] = vmean; morph[4] = vstd;  morph[5] = peak_loc;
        morph[6] = dmax;  morph[7] = dmin;  morph[8] = dabsmean;
        morph[9] = zcf;   morph[10] = ssq;  morph[11] = kurt; morph[12] = skew;
#pragma unroll
        for (int i = 0; i < 13; ++i) if (!isfinite(morph[i])) morph[i] = 0.0;
    }
    // morph group layernorm (f64) -> Fs (f32)
    {
        double mu = 0.0;
#pragma unroll
        for (int i = 0; i < 13; ++i) mu += morph[i];
        mu /= 13.0;
        double var = 0.0;
#pragma unroll
        for (int i = 0; i < 13; ++i) { double d = morph[i] - mu; var += d * d; }
        var /= 13.0;
        double inv = 1.0 / sqrt(var + 1e-5);
#pragma unroll
        for (int i = 0; i < 13; ++i)
            Fs[tid][i] = (float)((morph[i] - mu) * inv * (double)g_m[i] + (double)b_m[i]);
    }

    // compile-time memory clobber: ends pf's liveness so the DFT section
    // reloads its 30-float slices (L1/L2-hot) instead of keeping 60 VGPRs live.
    asm volatile("" ::: "memory");

    // ---- Welch PSD: f32 windowing (numpy-literal), f64 symmetric DFT with
    //      compile-time twiddle literals (no LDS, no int-mod, 32 indep chains) ----
    double psd[NF];
#pragma unroll
    for (int k = 0; k < NF; ++k) psd[k] = 0.0;

#pragma unroll
    for (int s = 0; s < NSEG; ++s) {
        float q[NPERSEG];
#pragma unroll
        for (int n = 0; n < NPERSEG; ++n) q[n] = xp[s * STEPW + n];

        float res = np_sum30_f32(q);
        float smean = res / 30.0f;           // f32 division, as np.mean
        float y[NPERSEG];
#pragma unroll
        for (int n = 0; n < NPERSEG; ++n) {
            const float hn = (float)(0.5 * (1.0 - TC[n]));   // folded f32 hann literal
            y[n] = (q[n] - smean) * hn;                      // f32 ops, as reference
        }

        double y0  = (double)y[0];
        double y15 = (double)y[15];
        double u[15], v[15];
#pragma unroll
        for (int m = 1; m < 15; ++m) {
            double a = (double)y[m], b = (double)y[NPERSEG - m];
            u[m] = a + b;            // cos-symmetric pair
            v[m] = a - b;            // sin-antisymmetric pair
        }

#pragma unroll
        for (int k = 0; k < NF; ++k) {
            double re = (k & 1) ? (y0 - y15) : (y0 + y15);
            double im = 0.0;
#pragma unroll
            for (int m = 1; m < 15; ++m) {
                const double tcv = TC[(k * m) % 30];   // compile-time constant
                const double tsv = TS[(k * m) % 30];   // compile-time constant
                re += u[m] * tcv;                      // ±1/±0.5 fold to add/sub/inline
                if (tsv != 0.0) im += v[m] * tsv;      // folded branch; skips exact zeros
            }
            double pw = re * re + im * im;
            pw *= INV_WN;                              // = /WIN_NORM to 1 ulp
            if (k != 0 && k != NF - 1) pw = pw + pw;   // * ONESIDED (exact x2)
            psd[k] += pw;                              // sum over segs
        }
    }
#pragma unroll
    for (int k = 0; k < NF; ++k) psd[k] = psd[k] * THIRD;   // .mean(-2) to 1 ulp

    // ---- spectral features, f64, literal decisions ----
    double total = np_sum16_f64(psd) + 1e-12;
    double invt = 1.0 / total;

    double band1 = psd[1] * invt;
    double band3 = ((psd[2] + psd[3]) + psd[4]) * invt;
    double b4s = 0.0;
#pragma unroll
    for (int k = 5; k <= 14; ++k) b4s += psd[k];
    double band4 = b4s * invt;

    int bk = 0; double bpv = psd[0];
#pragma unroll
    for (int k = 1; k < NF; ++k) if (psd[k] > bpv) { bpv = psd[k]; bk = k; }

    double th = 0.95 * total;
    int ek = 0;
    {
        double acc = 0.0; bool found = false;
#pragma unroll
        for (int k = 0; k < NF; ++k) {
            acc += psd[k];
            if (!found && acc >= th) { ek = k; found = true; }
        }
    }

    double ent = 0.0;
#pragma unroll
    for (int k = 0; k < NF; ++k) {
        double pn = psd[k] * invt;
        ent -= pn * log2(pn + 1e-12);
    }

    double spec[9];
    spec[0] = 0.0;
    spec[1] = band1;
    spec[2] = 0.0;
    spec[3] = band3;
    spec[4] = band4;
    spec[5] = (double)((float)((double)bk * 200.0 / 30.0));  // FREQS is f32
    spec[6] = (double)((float)((double)ek * 200.0 / 30.0));
    spec[7] = ent;
    spec[8] = total;
#pragma unroll
    for (int i = 0; i < 9; ++i) if (!isfinite(spec[i])) spec[i] = 0.0;

    // spec group layernorm (f64) -> Fs (f32)
    {
        double mu = 0.0;
#pragma unroll
        for (int i = 0; i < 9; ++i) mu += spec[i];
        mu /= 9.0;
        double var = 0.0;
#pragma unroll
        for (int i = 0; i < 9; ++i) { double d = spec[i] - mu; var += d * d; }
        var /= 9.0;
        double inv = 1.0 / sqrt(var + 1e-5);
#pragma unroll
        for (int i = 0; i < 9; ++i)
            Fs[tid][13 + i] = (float)((spec[i] - mu) * inv * (double)g_s[i] + (double)b_s[i]);
    }
    __syncthreads();

    // ================= phase 2: MLP (f32), 16 groups of TP=16 patches =================
    const int ch = tid;
    const int lane = tid & 63, wv = tid >> 6;
    const float bias2 = b2[ch];
    const float gch = g_o[ch], bch = b_o[ch];
    const long blk0 = (long)blockIdx.x * 256;

#pragma unroll 1
    for (int grp = 0; grp < NGRP; ++grp) {
        const int l0 = grp * TP;

#pragma unroll
        for (int v8 = 0; v8 < 8; ++v8) {
            int idx = tid + v8 * 256;
            int pp = idx >> 7, hc = idx & 127;
            float a = b1[hc];
#pragma unroll
            for (int k = 0; k < 22; ++k) a += Fs[l0 + pp][k] * W1[k * 128 + hc];
            Hs[pp][hc] = 0.5f * a * (1.0f + erff(a * 0.70710678118654752440f));
        }
        __syncthreads();

        float acc[TP];
#pragma unroll
        for (int pp = 0; pp < TP; ++pp) acc[pp] = bias2;

#pragma unroll 2
        for (int k = 0; k < 128; k += 4) {
            float w0 = W2[(k + 0) * 256 + ch];
            float w1 = W2[(k + 1) * 256 + ch];
            float w2 = W2[(k + 2) * 256 + ch];
            float w3 = W2[(k + 3) * 256 + ch];
#pragma unroll
            for (int pp = 0; pp < TP; ++pp) {
                const float4 h = *reinterpret_cast<const float4*>(&Hs[pp][k]);
                acc[pp] += h.x * w0;    // same k-ascending FMA order as before
                acc[pp] += h.y * w1;
                acc[pp] += h.z * w2;
                acc[pp] += h.w * w3;
            }
        }

#pragma unroll
        for (int pp = 0; pp < TP; ++pp) {
            float a = acc[pp], qq = acc[pp] * acc[pp];
            for (int off = 32; off; off >>= 1) {
                a += __shfl_xor(a, off);
                qq += __shfl_xor(qq, off);
            }
            if (lane == 0) { red1[pp][wv] = a; red2[pp][wv] = qq; }
        }
        __syncthreads();

#pragma unroll
        for (int pp = 0; pp < TP; ++pp) {
            float a = red1[pp][0] + red1[pp][1] + red1[pp][2] + red1[pp][3];
            float qq = red2[pp][0] + red2[pp][1] + red2[pp][2] + red2[pp][3];
            float mu = a * (1.0f / 256.0f);
            float var = qq * (1.0f / 256.0f) - mu * mu;
            float inv = rsqrtf(var + 1e-5f);
            out[(blk0 + l0 + pp) * 256 + ch] = (acc[pp] - mu) * inv * gch + bch;
        }
        __syncthreads();
    }
}

extern "C" void kernel_launch(void* const* d_in, const int* in_sizes, int n_in,
                              void* d_out, int out_size, void* d_ws, size_t ws_size,
                              hipStream_t stream) {
    const float* x   = (const float*)d_in[0];
    const float* g_m = (const float*)d_in[1];
    const float* b_m = (const float*)d_in[2];
    const float* g_s = (const float*)d_in[3];
    const float* b_s = (const float*)d_in[4];
    const float* W1  = (const float*)d_in[5];
    const float* b1  = (const float*)d_in[6];
    const float* W2  = (const float*)d_in[7];
    const float* b2  = (const float*)d_in[8];
    const float* g_o = (const float*)d_in[9];
    const float* b_o = (const float*)d_in[10];
    float* out = (float*)d_out;

    fused_kernel<<<NBLOCKS, 256, 0, stream>>>(
        x, g_m, b_m, g_s, b_s, W1, b1, W2, b2, g_o, b_o, out);
}

// Round 2
// 702.919 us; speedup vs baseline: 2.1530x; 1.4194x over previous
//
#include <hip/hip_runtime.h>
#include <math.h>

#define NPERSEG 30
#define STEPW 15
#define NSEG 3
#define NF 16
#define PATCH 60
#define STRIDE 30
#define NP_ROW 199
#define NBATCH 1024
#define T_LEN 6000
#define NPATCH_TOTAL (NBATCH * NP_ROW)   /* 203776 */
#define ABLK 128
#define NBLK_A (NPATCH_TOTAL / ABLK)     /* 1592 */
#define GB 16
#define NBLK_B (NPATCH_TOTAL / GB)       /* 12736 */

// f64 twiddles cos/sin(2*pi*m/30), correctly-rounded decimal literals.
constexpr double TC[30] = {
  1.0,
  0.97814760073380563793,
  0.91354545764260089550,
  0.80901699437494742410,
  0.66913060635885821383,
  0.5,
  0.30901699437494742410,
  0.10452846326765347140,
 -0.10452846326765347140,
 -0.30901699437494742410,
 -0.5,
 -0.66913060635885821383,
 -0.80901699437494742410,
 -0.91354545764260089550,
 -0.97814760073380563793,
 -1.0,
 -0.97814760073380563793,
 -0.91354545764260089550,
 -0.80901699437494742410,
 -0.66913060635885821383,
 -0.5,
 -0.30901699437494742410,
 -0.10452846326765347140,
  0.10452846326765347140,
  0.30901699437494742410,
  0.5,
  0.66913060635885821383,
  0.80901699437494742410,
  0.91354545764260089550,
  0.97814760073380563793,
};
constexpr double TS[30] = {
  0.0,
  0.20791169081775933710,
  0.40673664307580020775,
  0.58778525229247312917,
  0.74314482547739423501,
  0.86602540378443864676,
  0.95105651629515357212,
  0.99452189536827333692,
  0.99452189536827333692,
  0.95105651629515357212,
  0.86602540378443864676,
  0.74314482547739423501,
  0.58778525229247312917,
  0.40673664307580020775,
  0.20791169081775933710,
  0.0,
 -0.20791169081775933710,
 -0.40673664307580020775,
 -0.58778525229247312917,
 -0.74314482547739423501,
 -0.86602540378443864676,
 -0.95105651629515357212,
 -0.99452189536827333692,
 -0.99452189536827333692,
 -0.95105651629515357212,
 -0.86602540378443864676,
 -0.74314482547739423501,
 -0.58778525229247312917,
 -0.40673664307580020775,
 -0.20791169081775933710,
};
// WIN_NORM = 200 * sum(hann^2) = 2250 exactly (periodic hann, N=30).
constexpr double INV_WN = 1.0 / 2250.0;
constexpr double THIRD  = 1.0 / 3.0;

// numpy's pairwise f32 sum for n=30
__device__ __forceinline__ float np_sum30_f32(const float* a) {
    float r[8];
#pragma unroll
    for (int j = 0; j < 8; ++j) r[j] = a[j];
#pragma unroll
    for (int i = 8; i < 24; i += 8)
#pragma unroll
        for (int j = 0; j < 8; ++j) r[j] += a[i + j];
    float res = ((r[0] + r[1]) + (r[2] + r[3])) + ((r[4] + r[5]) + (r[6] + r[7]));
#pragma unroll
    for (int i = 24; i < 30; ++i) res += a[i];
    return res;
}

// numpy pairwise f64 sum for n=16
__device__ __forceinline__ double np_sum16_f64(const double* a) {
    double r[8];
#pragma unroll
    for (int j = 0; j < 8; ++j) r[j] = a[j] + a[8 + j];
    return ((r[0] + r[1]) + (r[2] + r[3])) + ((r[4] + r[5]) + (r[6] + r[7]));
}

// ===================== Kernel A: per-patch features (f64) =====================
// One thread = one patch. Arithmetic identical to the verified fused phase 1.
// Writes 22 f32 features into out[patch*256 + 0..21] (scratch; overwritten by B).
__global__ __launch_bounds__(ABLK, 4) void feat_kernel(
    const float* __restrict__ x,
    const float* __restrict__ g_m, const float* __restrict__ b_m,
    const float* __restrict__ g_s, const float* __restrict__ b_s,
    float* __restrict__ out)
{
    const int g   = blockIdx.x * ABLK + threadIdx.x;
    const int bb_ = g / NP_ROW;
    const int pi  = g - bb_ * NP_ROW;
    const float* xp = x + (size_t)bb_ * T_LEN + (size_t)pi * STRIDE;

    float f[22];

    // ---- morph (f64 continuous; discrete decisions input-exact) ----
    double morph[13];
    {
        float pf[PATCH];
#pragma unroll
        for (int n = 0; n < PATCH; ++n) pf[n] = xp[n];

        double vmax = (double)pf[0], vmin = vmax, vsum = 0.0;
#pragma unroll
        for (int n = 0; n < PATCH; ++n) {
            double v = (double)pf[n];
            vmax = fmax(vmax, v); vmin = fmin(vmin, v); vsum += v;
        }
        double vmean = vsum / 60.0;
        double s2 = 0.0, s3 = 0.0, s4 = 0.0, ssq = 0.0;
#pragma unroll
        for (int n = 0; n < PATCH; ++n) {
            double v = (double)pf[n];
            double c = v - vmean, c2 = c * c;
            s2 += c2; s3 += c2 * c; s4 += c2 * c2;
            ssq += v * v;
        }
        double m2 = s2 / 60.0, m3 = s3 / 60.0, m4 = s4 / 60.0;
        double vstd = sqrt(m2);

        int amax = 0; float aval = fabsf(pf[0]);
#pragma unroll
        for (int n = 1; n < PATCH; ++n) {
            float a = fabsf(pf[n]);
            if (a > aval) { aval = a; amax = n; }
        }
        double peak_loc = (double)((float)amax / 60.0f);

        double dmax = (double)pf[1] - (double)pf[0], dmin = dmax, dabssum = 0.0;
#pragma unroll
        for (int n = 0; n < PATCH - 1; ++n) {
            double d = (double)pf[n + 1] - (double)pf[n];
            dmax = fmax(dmax, d); dmin = fmin(dmin, d); dabssum += fabs(d);
        }
        double dabsmean = dabssum / 59.0;

        int zc = 0;
        {
            float v0 = pf[0] + 1e-10f;
            int prev = (v0 > 0.0f) - (v0 < 0.0f);
#pragma unroll
            for (int n = 1; n < PATCH; ++n) {
                float v = pf[n] + 1e-10f;
                int s = (v > 0.0f) - (v < 0.0f);
                if (s != prev) zc++;
                prev = s;
            }
        }
        double zcf = (double)zc / 60.0;
        double kurt = m4 / (m2 * m2) - 3.0;
        double skew = m3 / (m2 * sqrt(m2));

        morph[0] = vmax;  morph[1] = vmin;  morph[2] = vmax - vmin;
        morph[3] = vmean; morph[4] = vstd;  morph[5] = peak_loc;
        morph[6] = dmax;  morph[7] = dmin;  morph[8] = dabsmean;
        morph[9] = zcf;   morph[10] = ssq;  morph[11] = kurt; morph[12] = skew;
#pragma unroll
        for (int i = 0; i < 13; ++i) if (!isfinite(morph[i])) morph[i] = 0.0;
    }
    // morph group layernorm (f64) -> f[0..12] (f32)
    {
        double mu = 0.0;
#pragma unroll
        for (int i = 0; i < 13; ++i) mu += morph[i];
        mu /= 13.0;
        double var = 0.0;
#pragma unroll
        for (int i = 0; i < 13; ++i) { double d = morph[i] - mu; var += d * d; }
        var /= 13.0;
        double inv = 1.0 / sqrt(var + 1e-5);
#pragma unroll
        for (int i = 0; i < 13; ++i)
            f[i] = (float)((morph[i] - mu) * inv * (double)g_m[i] + (double)b_m[i]);
    }

    // end pf liveness -> DFT reloads its L1-hot 30-float slices
    asm volatile("" ::: "memory");

    // ---- Welch PSD: f32 windowing, f64 symmetric DFT, literal twiddles ----
    double psd[NF];
#pragma unroll
    for (int k = 0; k < NF; ++k) psd[k] = 0.0;

#pragma unroll
    for (int s = 0; s < NSEG; ++s) {
        float q[NPERSEG];
#pragma unroll
        for (int n = 0; n < NPERSEG; ++n) q[n] = xp[s * STEPW + n];

        float res = np_sum30_f32(q);
        float smean = res / 30.0f;
        float y[NPERSEG];
#pragma unroll
        for (int n = 0; n < NPERSEG; ++n) {
            const float hn = (float)(0.5 * (1.0 - TC[n]));
            y[n] = (q[n] - smean) * hn;
        }

        double y0  = (double)y[0];
        double y15 = (double)y[15];
        double u[15], v[15];
#pragma unroll
        for (int m = 1; m < 15; ++m) {
            double a = (double)y[m], b = (double)y[NPERSEG - m];
            u[m] = a + b;
            v[m] = a - b;
        }

#pragma unroll
        for (int k = 0; k < NF; ++k) {
            double re = (k & 1) ? (y0 - y15) : (y0 + y15);
            double im = 0.0;
#pragma unroll
            for (int m = 1; m < 15; ++m) {
                const double tcv = TC[(k * m) % 30];
                const double tsv = TS[(k * m) % 30];
                re += u[m] * tcv;
                if (tsv != 0.0) im += v[m] * tsv;
            }
            double pw = re * re + im * im;
            pw *= INV_WN;
            if (k != 0 && k != NF - 1) pw = pw + pw;
            psd[k] += pw;
        }
    }
#pragma unroll
    for (int k = 0; k < NF; ++k) psd[k] = psd[k] * THIRD;

    // ---- spectral features, f64 ----
    double total = np_sum16_f64(psd) + 1e-12;
    double invt = 1.0 / total;

    double band1 = psd[1] * invt;
    double band3 = ((psd[2] + psd[3]) + psd[4]) * invt;
    double b4s = 0.0;
#pragma unroll
    for (int k = 5; k <= 14; ++k) b4s += psd[k];
    double band4 = b4s * invt;

    int bk = 0; double bpv = psd[0];
#pragma unroll
    for (int k = 1; k < NF; ++k) if (psd[k] > bpv) { bpv = psd[k]; bk = k; }

    double th = 0.95 * total;
    int ek = 0;
    {
        double acc = 0.0; bool found = false;
#pragma unroll
        for (int k = 0; k < NF; ++k) {
            acc += psd[k];
            if (!found && acc >= th) { ek = k; found = true; }
        }
    }

    double ent = 0.0;
#pragma unroll
    for (int k = 0; k < NF; ++k) {
        double pn = psd[k] * invt;
        ent -= pn * log2(pn + 1e-12);
    }

    double spec[9];
    spec[0] = 0.0;
    spec[1] = band1;
    spec[2] = 0.0;
    spec[3] = band3;
    spec[4] = band4;
    spec[5] = (double)((float)((double)bk * 200.0 / 30.0));
    spec[6] = (double)((float)((double)ek * 200.0 / 30.0));
    spec[7] = ent;
    spec[8] = total;
#pragma unroll
    for (int i = 0; i < 9; ++i) if (!isfinite(spec[i])) spec[i] = 0.0;

    // spec group layernorm (f64) -> f[13..21] (f32)
    {
        double mu = 0.0;
#pragma unroll
        for (int i = 0; i < 9; ++i) mu += spec[i];
        mu /= 9.0;
        double var = 0.0;
#pragma unroll
        for (int i = 0; i < 9; ++i) { double d = spec[i] - mu; var += d * d; }
        var /= 9.0;
        double inv = 1.0 / sqrt(var + 1e-5);
#pragma unroll
        for (int i = 0; i < 9; ++i)
            f[13 + i] = (float)((spec[i] - mu) * inv * (double)g_s[i] + (double)b_s[i]);
    }

    // ---- store 22 features into the out row (1KB-aligned -> float4 ok) ----
    float* op = out + (size_t)g * 256;
    *reinterpret_cast<float4*>(op +  0) = make_float4(f[0],  f[1],  f[2],  f[3]);
    *reinterpret_cast<float4*>(op +  4) = make_float4(f[4],  f[5],  f[6],  f[7]);
    *reinterpret_cast<float4*>(op +  8) = make_float4(f[8],  f[9],  f[10], f[11]);
    *reinterpret_cast<float4*>(op + 12) = make_float4(f[12], f[13], f[14], f[15]);
    *reinterpret_cast<float4*>(op + 16) = make_float4(f[16], f[17], f[18], f[19]);
    *reinterpret_cast<float2*>(op + 20) = make_float2(f[20], f[21]);
}

// ===================== Kernel B: MLP (f32) =====================
// One block = 16 patches. Reads its own patches' feature rows from out,
// barriers, then overwrites them with the final embedding.
// W2 register blocking: thread owns 4 ch x 4 pp; ch = (tid&63)+64c,
// pp = 4*wave + p -> each wave holds all 256 ch for its 4 patches, so the
// output layernorm is a single in-wave shuffle reduction (no LDS round-trip).
// Per-accumulator k-order is unchanged vs the verified kernel.
__global__ __launch_bounds__(256, 4) void mlp_kernel(
    const float* __restrict__ W1, const float* __restrict__ b1,
    const float* __restrict__ W2, const float* __restrict__ b2,
    const float* __restrict__ g_o, const float* __restrict__ b_o,
    float* __restrict__ out)
{
    __shared__ float Fsl[GB][22];
    __shared__ float Hs[GB][128];

    const int tid = threadIdx.x;
    const long p0 = (long)blockIdx.x * GB;

    // stage this block's feature rows
    for (int idx = tid; idx < GB * 22; idx += 256) {
        int j = idx / 22, i = idx - j * 22;
        Fsl[j][i] = out[(p0 + j) * 256 + i];
    }
    __syncthreads();

    // ---- W1 + exact gelu -> Hs ----
    {
        const int hc = tid & 127;
        const int ppb = tid >> 7;
        float w1c[22];
#pragma unroll
        for (int k = 0; k < 22; ++k) w1c[k] = W1[k * 128 + hc];   // hoisted column
        const float b1v = b1[hc];
#pragma unroll
        for (int v = 0; v < 8; ++v) {
            const int pp = ppb + 2 * v;
            float a = b1v;
#pragma unroll
            for (int k = 0; k < 22; ++k) a += Fsl[pp][k] * w1c[k];  // b32 broadcast
            Hs[pp][hc] = 0.5f * a * (1.0f + erff(a * 0.70710678118654752440f));
        }
    }
    __syncthreads();

    // ---- W2 GEMM: 4 ch x 4 pp per thread ----
    const int cb = tid & 63;
    const int wv = tid >> 6;
    float go[4], bo[4];
    float acc[4][4];   // [c][p]
#pragma unroll
    for (int c = 0; c < 4; ++c) {
        go[c] = g_o[cb + 64 * c];
        bo[c] = b_o[cb + 64 * c];
        const float b2v = b2[cb + 64 * c];
#pragma unroll
        for (int p = 0; p < 4; ++p) acc[c][p] = b2v;
    }

#pragma unroll 2
    for (int k = 0; k < 128; k += 4) {
        float4 h[4];
#pragma unroll
        for (int p = 0; p < 4; ++p)
            h[p] = *reinterpret_cast<const float4*>(&Hs[4 * wv + p][k]);  // broadcast b128
        float w[4][4];
#pragma unroll
        for (int kk = 0; kk < 4; ++kk)
#pragma unroll
            for (int c = 0; c < 4; ++c)
                w[kk][c] = W2[(k + kk) * 256 + cb + 64 * c];   // coalesced 256B
        // k-ascending FMA order per accumulator (bit-identical to previous)
#pragma unroll
        for (int kk = 0; kk < 4; ++kk)
#pragma unroll
            for (int c = 0; c < 4; ++c) {
#pragma unroll
                for (int p = 0; p < 4; ++p) {
                    const float hv = (kk == 0) ? h[p].x : (kk == 1) ? h[p].y
                                   : (kk == 2) ? h[p].z : h[p].w;
                    acc[c][p] += hv * w[kk][c];
                }
            }
    }

    // ---- 256-ch layernorm: in-wave reduction, then store ----
#pragma unroll
    for (int p = 0; p < 4; ++p) {
        float s = (acc[0][p] + acc[1][p]) + (acc[2][p] + acc[3][p]);
        float q = (acc[0][p] * acc[0][p] + acc[1][p] * acc[1][p])
                + (acc[2][p] * acc[2][p] + acc[3][p] * acc[3][p]);
        for (int off = 32; off; off >>= 1) {
            s += __shfl_xor(s, off);
            q += __shfl_xor(q, off);
        }
        const float mu  = s * (1.0f / 256.0f);
        const float var = q * (1.0f / 256.0f) - mu * mu;
        const float inv = rsqrtf(var + 1e-5f);
        const long row = (p0 + 4 * wv + p) * 256;
#pragma unroll
        for (int c = 0; c < 4; ++c)
            out[row + cb + 64 * c] = (acc[c][p] - mu) * inv * go[c] + bo[c];
    }
}

extern "C" void kernel_launch(void* const* d_in, const int* in_sizes, int n_in,
                              void* d_out, int out_size, void* d_ws, size_t ws_size,
                              hipStream_t stream) {
    const float* x   = (const float*)d_in[0];
    const float* g_m = (const float*)d_in[1];
    const float* b_m = (const float*)d_in[2];
    const float* g_s = (const float*)d_in[3];
    const float* b_s = (const float*)d_in[4];
    const float* W1  = (const float*)d_in[5];
    const float* b1  = (const float*)d_in[6];
    const float* W2  = (const float*)d_in[7];
    const float* b2  = (const float*)d_in[8];
    const float* g_o = (const float*)d_in[9];
    const float* b_o = (const float*)d_in[10];
    float* out = (float*)d_out;

    feat_kernel<<<NBLK_A, ABLK, 0, stream>>>(x, g_m, b_m, g_s, b_s, out);
    mlp_kernel<<<NBLK_B, 256, 0, stream>>>(W1, b1, W2, b2, g_o, b_o, out);
}